// Round 11
// baseline (74.876 us; speedup 1.0000x reference)
//
#include <hip/hip_runtime.h>

#define B   32
#define V   1024
#define HID 768
#define OUT 256
#define NVC 16   // v-chunks in colsum
#define NWC 32   // w-chunks in gather (proven round-4 value)

// Kernel 1: partial[b][vc][w] = sum over 64 v-rows of adj[b][v][w].
// grid (B, NVC), 256 threads, float4/lane -> block streams a contiguous
// 256KB region 4KB/iter (proven row-buffer-friendly pattern, rounds 0/3/4).
__global__ void colsum_partial_kernel(const float* __restrict__ adj,
                                      float* __restrict__ partial) {
    const int b   = blockIdx.x;
    const int vc  = blockIdx.y;
    const int tid = threadIdx.x;
    const float4* adj4 = reinterpret_cast<const float4*>(adj)
                       + (size_t)(b * V + vc * 64) * (V / 4);
    float4 acc = make_float4(0.f, 0.f, 0.f, 0.f);
    #pragma unroll 8
    for (int v = 0; v < 64; ++v) {
        float4 a = adj4[(size_t)v * (V / 4) + tid];
        acc.x += a.x; acc.y += a.y; acc.z += a.z; acc.w += a.w;
    }
    reinterpret_cast<float4*>(partial + (size_t)(b * NVC + vc) * V)[tid] = acc;
}

// Kernel 2: hpart[b][wc][k] = sum over 32 w's of c[b][w] * emb[ids[b][w]][k],
// where c[b][w] = sum_vc partial[b][vc][w] (reduced in prologue, L2-resident).
// grid (B, NWC), 192 threads: float4/lane covers a full HID=768 row.
// Plain stores to a private slice -> no atomics anywhere. (Proven, round 4.)
__global__ void gather_wsum_kernel(const float* __restrict__ emb,
                                   const int* __restrict__ ids,
                                   const float* __restrict__ partial,
                                   float* __restrict__ hpart) {
    const int b  = blockIdx.x;
    const int wc = blockIdx.y;
    const int t  = threadIdx.x;         // 0..191
    __shared__ float sm[4][32];
    __shared__ float c_s[32];
    __shared__ int   ids_s[32];
    if (t < 128) {
        const int wi = t & 31, q = t >> 5;
        float s = 0.f;
        #pragma unroll
        for (int j = 0; j < 4; ++j)
            s += partial[(size_t)(b * NVC + q * 4 + j) * V + wc * 32 + wi];
        sm[q][wi] = s;
    }
    if (t < 32)
        ids_s[t] = ids[b * V + wc * 32 + t];
    __syncthreads();
    if (t < 32)
        c_s[t] = sm[0][t] + sm[1][t] + sm[2][t] + sm[3][t];
    __syncthreads();
    float4 acc = make_float4(0.f, 0.f, 0.f, 0.f);
    #pragma unroll 8
    for (int i = 0; i < 32; ++i) {
        const float4* T4 = reinterpret_cast<const float4*>(emb + (size_t)ids_s[i] * HID);
        const float4 a = T4[t];
        const float  s = c_s[i];
        acc.x += s * a.x; acc.y += s * a.y; acc.z += s * a.z; acc.w += s * a.w;
    }
    reinterpret_cast<float4*>(hpart + (size_t)(b * NWC + wc) * HID)[t] = acc;
}

// Kernel 3: out[b][:] = fc_b + (1/V) * (h[b] @ fc_w^T),
// h reduced from NWC hpart chunks into LDS ONCE per sample (single read of
// the 96KB slice, vs 8x re-read in the (B,8) variant).
// grid (B), 512 threads = 8 waves; each wave computes 32 outputs.
__global__ void fc_reduce_kernel(const float* __restrict__ hpart,
                                 const float* __restrict__ fc_w,
                                 const float* __restrict__ fc_b,
                                 float* __restrict__ out) {
    const int b = blockIdx.x;
    const int t = threadIdx.x;          // 0..511
    __shared__ float h_s[HID];
    {
        const float* hp = hpart + (size_t)b * NWC * HID;
        float s0 = 0.f, s1 = 0.f;
        #pragma unroll 8
        for (int j = 0; j < NWC; ++j) {
            s0 += hp[j * HID + t];
            if (t < HID - 512) s1 += hp[j * HID + t + 512];
        }
        h_s[t] = s0;
        if (t < HID - 512) h_s[t + 512] = s1;
    }
    __syncthreads();
    const int wave = t >> 6, lane = t & 63;
    #pragma unroll
    for (int it = 0; it < OUT / 8; ++it) {   // 32 outputs per wave
        const int o = it * 8 + wave;
        const float* wrow = fc_w + (size_t)o * HID;
        float acc = 0.f;
        #pragma unroll
        for (int k = 0; k < HID / 64; ++k)
            acc += wrow[k * 64 + lane] * h_s[k * 64 + lane];
        #pragma unroll
        for (int off = 32; off > 0; off >>= 1)
            acc += __shfl_down(acc, off, 64);
        if (lane == 0)
            out[b * OUT + o] = fc_b[o] + acc * (1.0f / V);
    }
}

extern "C" void kernel_launch(void* const* d_in, const int* in_sizes, int n_in,
                              void* d_out, int out_size, void* d_ws, size_t ws_size,
                              hipStream_t stream) {
    const float* emb  = (const float*)d_in[0];
    const float* adj  = (const float*)d_in[1];
    const float* fc_w = (const float*)d_in[2];
    const float* fc_b = (const float*)d_in[3];
    const int*   ids  = (const int*)d_in[4];
    float* out = (float*)d_out;

    float* partial = (float*)d_ws;              // [B][NVC][V]    2.0 MB
    float* hpart   = partial + B * NVC * V;     // [B][NWC][HID]  3.1 MB

    colsum_partial_kernel<<<dim3(B, NVC), 256, 0, stream>>>(adj, partial);
    gather_wsum_kernel<<<dim3(B, NWC), 192, 0, stream>>>(emb, ids, partial, hpart);
    fc_reduce_kernel<<<dim3(B), 512, 0, stream>>>(hpart, fc_w, fc_b, out);
}

// Round 12
// 49.455 us; speedup vs baseline: 1.5140x; 1.5140x over previous
//
#include <hip/hip_runtime.h>

#define B   32
#define V   1024
#define HID 768
#define OUT 256
#define NVC 16   // v-chunks in colsum
#define NWC 32   // w-chunks in gather

// ---- Proven round-4 optimum: 3 dispatches, partial buffers, no atomics ----
// Ladder: 59.8 (r0) -> 54.0 (r3: no memset, row-contiguous partials)
//      -> 49.4 (r4: no atomics anywhere, (B,8) fc).
// Refuted levers: col-sliced adj reads (r2 +13%), grid.sync fusion (r5 5x),
// spin-wait fusion (r6 hang), nt-hint cache steering (r8 +4%), fan-in fence
// fusion (r9 3.7x), NWC=64 occupancy (r10 +5%), single-block fc (r11 +50%).

// Kernel 1: partial[b][vc][w] = sum over 64 v-rows of adj[b][v][w].
// grid (B, NVC), 256 threads, float4/lane -> 4KB contiguous per iter
// (row-buffer friendly). 134MB stream, BW-bound.
__global__ void colsum_partial_kernel(const float* __restrict__ adj,
                                      float* __restrict__ partial) {
    const int b   = blockIdx.x;
    const int vc  = blockIdx.y;
    const int tid = threadIdx.x;
    const float4* adj4 = reinterpret_cast<const float4*>(adj)
                       + (size_t)(b * V + vc * 64) * (V / 4);
    float4 acc = make_float4(0.f, 0.f, 0.f, 0.f);
    #pragma unroll 8
    for (int v = 0; v < 64; ++v) {
        float4 a = adj4[(size_t)v * (V / 4) + tid];
        acc.x += a.x; acc.y += a.y; acc.z += a.z; acc.w += a.w;
    }
    reinterpret_cast<float4*>(partial + (size_t)(b * NVC + vc) * V)[tid] = acc;
}

// Kernel 2: hpart[b][wc][k] = sum over 32 w's of c[b][w] * emb[ids[b][w]][k],
// where c[b][w] = sum_vc partial[b][vc][w] (reduced in prologue, L2-resident).
// grid (B, NWC), 192 threads: float4/lane covers a full HID=768 row.
// Plain stores to a private slice -> no atomics anywhere.
__global__ void gather_wsum_kernel(const float* __restrict__ emb,
                                   const int* __restrict__ ids,
                                   const float* __restrict__ partial,
                                   float* __restrict__ hpart) {
    const int b  = blockIdx.x;
    const int wc = blockIdx.y;
    const int t  = threadIdx.x;         // 0..191
    __shared__ float sm[4][32];
    __shared__ float c_s[32];
    __shared__ int   ids_s[32];
    if (t < 128) {
        const int wi = t & 31, q = t >> 5;
        float s = 0.f;
        #pragma unroll
        for (int j = 0; j < 4; ++j)
            s += partial[(size_t)(b * NVC + q * 4 + j) * V + wc * 32 + wi];
        sm[q][wi] = s;
    }
    if (t < 32)
        ids_s[t] = ids[b * V + wc * 32 + t];
    __syncthreads();
    if (t < 32)
        c_s[t] = sm[0][t] + sm[1][t] + sm[2][t] + sm[3][t];
    __syncthreads();
    float4 acc = make_float4(0.f, 0.f, 0.f, 0.f);
    #pragma unroll 8
    for (int i = 0; i < 32; ++i) {
        const float4* T4 = reinterpret_cast<const float4*>(emb + (size_t)ids_s[i] * HID);
        const float4 a = T4[t];
        const float  s = c_s[i];
        acc.x += s * a.x; acc.y += s * a.y; acc.z += s * a.z; acc.w += s * a.w;
    }
    reinterpret_cast<float4*>(hpart + (size_t)(b * NWC + wc) * HID)[t] = acc;
}

// Kernel 3: out[b][o] = fc_b[o] + (1/V) * dot(h[b][:], fc_w[o][:]),
// h reduced from 32 hpart chunks into LDS once per block.
// grid (B, 8), 256 threads: 4 waves x 8 iters = 32 outputs per block.
// (256 blocks: enough parallelism; hpart re-reads are L2-served and free.)
__global__ void fc_reduce_kernel(const float* __restrict__ hpart,
                                 const float* __restrict__ fc_w,
                                 const float* __restrict__ fc_b,
                                 float* __restrict__ out) {
    const int b  = blockIdx.x;
    const int og = blockIdx.y;
    const int t  = threadIdx.x;
    __shared__ float h_s[HID];
    {
        const float* hp = hpart + (size_t)b * NWC * HID;
        float s0 = 0.f, s1 = 0.f, s2 = 0.f;
        #pragma unroll 8
        for (int j = 0; j < NWC; ++j) {
            s0 += hp[j * HID + t];
            s1 += hp[j * HID + t + 256];
            s2 += hp[j * HID + t + 512];
        }
        h_s[t] = s0; h_s[t + 256] = s1; h_s[t + 512] = s2;
    }
    __syncthreads();
    const int wave = t >> 6, lane = t & 63;
    #pragma unroll
    for (int it = 0; it < 8; ++it) {
        const int o = og * 32 + it * 4 + wave;
        const float* wrow = fc_w + (size_t)o * HID;
        float acc = 0.f;
        #pragma unroll
        for (int k = 0; k < HID / 64; ++k)
            acc += wrow[k * 64 + lane] * h_s[k * 64 + lane];
        #pragma unroll
        for (int off = 32; off > 0; off >>= 1)
            acc += __shfl_down(acc, off, 64);
        if (lane == 0)
            out[b * OUT + o] = fc_b[o] + acc * (1.0f / V);
    }
}

extern "C" void kernel_launch(void* const* d_in, const int* in_sizes, int n_in,
                              void* d_out, int out_size, void* d_ws, size_t ws_size,
                              hipStream_t stream) {
    const float* emb  = (const float*)d_in[0];
    const float* adj  = (const float*)d_in[1];
    const float* fc_w = (const float*)d_in[2];
    const float* fc_b = (const float*)d_in[3];
    const int*   ids  = (const int*)d_in[4];
    float* out = (float*)d_out;

    float* partial = (float*)d_ws;              // [B][NVC][V]    2.0 MB
    float* hpart   = partial + B * NVC * V;     // [B][NWC][HID]  3.1 MB

    colsum_partial_kernel<<<dim3(B, NVC), 256, 0, stream>>>(adj, partial);
    gather_wsum_kernel<<<dim3(B, NWC), 192, 0, stream>>>(emb, ids, partial, hpart);
    fc_reduce_kernel<<<dim3(B, 8), 256, 0, stream>>>(hpart, fc_w, fc_b, out);
}